// Round 1
// baseline (4668.890 us; speedup 1.0000x reference)
//
#include <hip/hip_runtime.h>

#define IN   6
#define H    64
#define G    256   // 4*H
#define TT   512
#define NB   8
#define OUTD 3
#define BTOT 4096

__device__ __forceinline__ float sigf(float v)  { return 1.0f / (1.0f + __expf(-v)); }
__device__ __forceinline__ float tanhf_(float v){ return 1.0f - 2.0f / (1.0f + __expf(2.0f * v)); }

__launch_bounds__(256, 2)
__global__ void lstm_fused(const float* __restrict__ x,
                           const float* __restrict__ Wih0, const float* __restrict__ Whh0,
                           const float* __restrict__ bih0, const float* __restrict__ bhh0,
                           const float* __restrict__ Wih1, const float* __restrict__ Whh1,
                           const float* __restrict__ bih1, const float* __restrict__ bhh1,
                           const float* __restrict__ Wfc,  const float* __restrict__ bfc,
                           float* __restrict__ out)
{
    __shared__ __align__(16) float h0[NB][H];
    __shared__ __align__(16) float c0[NB][H];
    __shared__ __align__(16) float h1[NB][H];
    __shared__ __align__(16) float c1[NB][H];
    __shared__ __align__(16) float gates[NB][G];
    __shared__ float xs[NB][IN];

    const int tid = threadIdx.x;
    const int g   = tid;                  // gate row this thread owns
    const int b0  = blockIdx.x * NB;      // first batch element of this block

    // gate row type is wave-uniform: rows [128,192) are the tanh 'g' gate
    const bool is_tanh = ((tid >> 6) == 2);

    // ---- load per-thread weight rows into registers ----
    float wi0[IN], wh0[H], wi1[H], wh1[H];
    #pragma unroll
    for (int f = 0; f < IN; ++f) wi0[f] = Wih0[g * IN + f];
    #pragma unroll
    for (int j = 0; j < H; ++j) wh0[j] = Whh0[g * H + j];
    #pragma unroll
    for (int j = 0; j < H; ++j) wi1[j] = Wih1[g * H + j];
    #pragma unroll
    for (int j = 0; j < H; ++j) wh1[j] = Whh1[g * H + j];
    const float bias0 = bih0[g] + bhh0[g];
    const float bias1 = bih1[g] + bhh1[g];

    // ---- zero-init states ----
    {
        float* p0 = &h0[0][0]; float* p1 = &c0[0][0];
        float* p2 = &h1[0][0]; float* p3 = &c1[0][0];
        #pragma unroll
        for (int k = 0; k < (NB * H) / 256; ++k) {
            p0[tid + k * 256] = 0.0f; p1[tid + k * 256] = 0.0f;
            p2[tid + k * 256] = 0.0f; p3[tid + k * 256] = 0.0f;
        }
    }

    // ---- x prefetch setup (threads 0..47 each own one (bb,f) slot) ----
    const bool loader = (tid < NB * IN);
    const int lbb = tid / IN;
    const int lf  = tid - lbb * IN;
    float xbuf = 0.0f;
    if (loader) xbuf = x[((size_t)(b0 + lbb) * TT + 0) * IN + lf];

    for (int t = 0; t < TT; ++t) {
        if (loader) xs[lbb][lf] = xbuf;
        __syncthreads();   // x visible; prev-step h/c writes visible

        // prefetch next step's x (hidden behind this step's compute)
        if (loader) {
            int tn = (t + 1 < TT) ? (t + 1) : t;
            xbuf = x[((size_t)(b0 + lbb) * TT + tn) * IN + lf];
        }

        // ---- Phase A: layer-0 gates ----
        for (int bb = 0; bb < NB; ++bb) {
            float a = bias0;
            #pragma unroll
            for (int f = 0; f < IN; ++f) a += wi0[f] * xs[bb][f];
            const float4* hv = (const float4*)h0[bb];
            #pragma unroll
            for (int j4 = 0; j4 < H / 4; ++j4) {
                float4 h4 = hv[j4];
                a += wh0[4 * j4 + 0] * h4.x;
                a += wh0[4 * j4 + 1] * h4.y;
                a += wh0[4 * j4 + 2] * h4.z;
                a += wh0[4 * j4 + 3] * h4.w;
            }
            gates[bb][g] = is_tanh ? tanhf_(a) : sigf(a);
        }
        __syncthreads();

        // ---- Phase B: layer-0 state update ----
        #pragma unroll
        for (int k = 0; k < (NB * H) / 256; ++k) {
            int idx = tid + k * 256;
            int bb = idx >> 6, j = idx & 63;
            float gi = gates[bb][j];
            float gf = gates[bb][64 + j];
            float gg = gates[bb][128 + j];
            float go = gates[bb][192 + j];
            float c = gf * c0[bb][j] + gi * gg;
            c0[bb][j] = c;
            h0[bb][j] = go * tanhf_(c);
        }
        __syncthreads();

        // ---- Phase C: layer-1 gates (input = new h0, recurrent = h1) ----
        for (int bb = 0; bb < NB; ++bb) {
            float a = bias1;
            const float4* iv = (const float4*)h0[bb];
            const float4* hv = (const float4*)h1[bb];
            #pragma unroll
            for (int j4 = 0; j4 < H / 4; ++j4) {
                float4 i4 = iv[j4];
                a += wi1[4 * j4 + 0] * i4.x;
                a += wi1[4 * j4 + 1] * i4.y;
                a += wi1[4 * j4 + 2] * i4.z;
                a += wi1[4 * j4 + 3] * i4.w;
            }
            #pragma unroll
            for (int j4 = 0; j4 < H / 4; ++j4) {
                float4 h4 = hv[j4];
                a += wh1[4 * j4 + 0] * h4.x;
                a += wh1[4 * j4 + 1] * h4.y;
                a += wh1[4 * j4 + 2] * h4.z;
                a += wh1[4 * j4 + 3] * h4.w;
            }
            gates[bb][g] = is_tanh ? tanhf_(a) : sigf(a);
        }
        __syncthreads();

        // ---- Phase D: layer-1 state update ----
        #pragma unroll
        for (int k = 0; k < (NB * H) / 256; ++k) {
            int idx = tid + k * 256;
            int bb = idx >> 6, j = idx & 63;
            float gi = gates[bb][j];
            float gf = gates[bb][64 + j];
            float gg = gates[bb][128 + j];
            float go = gates[bb][192 + j];
            float c = gf * c1[bb][j] + gi * gg;
            c1[bb][j] = c;
            h1[bb][j] = go * tanhf_(c);
        }
        // no barrier: next iteration's top-of-loop barrier covers it
    }

    __syncthreads();

    // ---- FC epilogue: out[b][o] = h1_last[b] . Wfc[o] + bfc[o] ----
    if (tid < NB * OUTD) {
        int bb = tid / OUTD;
        int o  = tid - bb * OUTD;
        float a = bfc[o];
        #pragma unroll
        for (int j = 0; j < H; ++j) a += Wfc[o * H + j] * h1[bb][j];
        out[(size_t)(b0 + bb) * OUTD + o] = a;
    }
}

extern "C" void kernel_launch(void* const* d_in, const int* in_sizes, int n_in,
                              void* d_out, int out_size, void* d_ws, size_t ws_size,
                              hipStream_t stream) {
    const float* x    = (const float*)d_in[0];
    const float* Wih0 = (const float*)d_in[1];
    const float* Whh0 = (const float*)d_in[2];
    const float* bih0 = (const float*)d_in[3];
    const float* bhh0 = (const float*)d_in[4];
    const float* Wih1 = (const float*)d_in[5];
    const float* Whh1 = (const float*)d_in[6];
    const float* bih1 = (const float*)d_in[7];
    const float* bhh1 = (const float*)d_in[8];
    const float* Wfc  = (const float*)d_in[9];
    const float* bfc  = (const float*)d_in[10];

    dim3 grid(BTOT / NB);
    dim3 block(256);
    lstm_fused<<<grid, block, 0, stream>>>(x, Wih0, Whh0, bih0, bhh0,
                                           Wih1, Whh1, bih1, bhh1,
                                           Wfc, bfc, (float*)d_out);
}

// Round 2
// 1459.006 us; speedup vs baseline: 3.2000x; 3.2000x over previous
//
#include <hip/hip_runtime.h>

#define H    64
#define G    256
#define TT   512
#define NB   16
#define OUTD 3
#define BTOT 4096
#define INF  6

typedef _Float16 f16;
typedef _Float16 f16x8 __attribute__((ext_vector_type(8)));
typedef float    f32x4 __attribute__((ext_vector_type(4)));

// LDS row strides (elements), padded for bank-conflict freedom
#define AS 168   // fp16/row: cols 0-63 h0, 64-127 h1, 128-133 x, rest pad/zero
#define GS 258   // f32/row for the gate pre-activation buffer

__device__ __forceinline__ float sigf(float v)  { return 1.0f / (1.0f + __expf(-v)); }
__device__ __forceinline__ float tanh_(float v) { return 1.0f - 2.0f / (1.0f + __expf(2.0f * v)); }

__launch_bounds__(256, 1)
__global__ void lstm_mfma(const float* __restrict__ x,
                          const float* __restrict__ Wih0, const float* __restrict__ Whh0,
                          const float* __restrict__ bih0, const float* __restrict__ bhh0,
                          const float* __restrict__ Wih1, const float* __restrict__ Whh1,
                          const float* __restrict__ bih1, const float* __restrict__ bhh1,
                          const float* __restrict__ Wfc,  const float* __restrict__ bfc,
                          float* __restrict__ out)
{
    __shared__ __align__(16) f16   Ahi[NB * AS];
    __shared__ __align__(16) f16   Alo[NB * AS];
    __shared__ __align__(16) float gl[NB * GS];

    const int t    = threadIdx.x;
    const int lane = t & 63;
    const int w    = t >> 6;        // wave 0..3, owns N-tiles 4w..4w+3 (gate cols 64w..64w+63)
    const int l15  = t & 15;
    const int q    = (t >> 4) & 3;  // quad within wave
    const int b0   = blockIdx.x * NB;

    // ---- B fragments (weights), fp16, resident in registers ----
    // B[k][n] layout: n = lane&15 (+16*tile), k = quad*8 + j  → frag = W[n][k..k+8) (row-major W)
    f16x8 bL0[3][4];   // kt 0,1: Whh0 k∈[0,64); kt 2: x-tile from Wih0 (k<6 valid, rest 0)
    f16x8 bL1[4][4];   // kt 0,1: Wih1 (input = h0); kt 2,3: Whh1 (recurrent h1)
    #pragma unroll
    for (int i = 0; i < 4; ++i) {
        const int n = 64 * w + 16 * i + l15;
        #pragma unroll
        for (int kt = 0; kt < 2; ++kt) {
            f16x8 v0, v1, v2;
            #pragma unroll
            for (int j = 0; j < 8; ++j) {
                v0[j] = (f16)Whh0[n * H + kt * 32 + q * 8 + j];
                v1[j] = (f16)Wih1[n * H + kt * 32 + q * 8 + j];
                v2[j] = (f16)Whh1[n * H + kt * 32 + q * 8 + j];
            }
            bL0[kt][i]     = v0;
            bL1[kt][i]     = v1;
            bL1[kt + 2][i] = v2;
        }
        f16x8 vx;
        #pragma unroll
        for (int j = 0; j < 8; ++j)
            vx[j] = (q == 0 && j < INF) ? (f16)Wih0[n * INF + j] : (f16)0.0f;
        bL0[2][i] = vx;
    }

    // ---- per-thread biases for the update phases (thread owns column j=lane) ----
    float bu0[4], bu1[4];
    #pragma unroll
    for (int g4 = 0; g4 < 4; ++g4) {
        bu0[g4] = bih0[g4 * 64 + lane] + bhh0[g4 * 64 + lane];
        bu1[g4] = bih1[g4 * 64 + lane] + bhh1[g4 * 64 + lane];
    }

    // ---- cell state registers: thread owns rows b = w + 4k, column j = lane ----
    float c0r[4] = {0.f, 0.f, 0.f, 0.f};
    float c1r[4] = {0.f, 0.f, 0.f, 0.f};

    // ---- zero A planes (h=0 init + zero padding), store x(t=0) ----
    for (int idx = t; idx < NB * AS; idx += 256) {
        Ahi[idx] = (f16)0.0f;
        Alo[idx] = (f16)0.0f;
    }
    const bool loader = (t < NB * INF);
    const int  xb = t / INF;
    const int  xf = t - xb * INF;
    if (loader) {
        float v = x[((size_t)(b0 + xb) * TT + 0) * INF + xf];
        f16 vh = (f16)v;
        Ahi[xb * AS + 128 + xf] = vh;
        Alo[xb * AS + 128 + xf] = (f16)(v - (float)vh);
    }
    float xpre = 0.0f;
    __syncthreads();

    const int arow = l15 * AS;
    const int koff = q * 8;

    for (int tt = 0; tt < TT; ++tt) {
        // prefetch next x (consumed in phase D)
        if (loader) {
            int tn = (tt + 1 < TT) ? (tt + 1) : (TT - 1);
            xpre = x[((size_t)(b0 + xb) * TT + tn) * INF + xf];
        }

        // ======== Phase A: layer-0 MFMA: gates = [h0 | x] @ B_L0 ========
        {
            f16x8 a0h = *(const f16x8*)&Ahi[arow + 0   + koff];
            f16x8 a0l = *(const f16x8*)&Alo[arow + 0   + koff];
            f16x8 a1h = *(const f16x8*)&Ahi[arow + 32  + koff];
            f16x8 a1l = *(const f16x8*)&Alo[arow + 32  + koff];
            f16x8 axh = *(const f16x8*)&Ahi[arow + 128 + koff];
            f16x8 axl = *(const f16x8*)&Alo[arow + 128 + koff];
            #pragma unroll
            for (int i = 0; i < 4; ++i) {
                f32x4 acc = {0.f, 0.f, 0.f, 0.f};
                acc = __builtin_amdgcn_mfma_f32_16x16x32_f16(a0h, bL0[0][i], acc, 0, 0, 0);
                acc = __builtin_amdgcn_mfma_f32_16x16x32_f16(a0l, bL0[0][i], acc, 0, 0, 0);
                acc = __builtin_amdgcn_mfma_f32_16x16x32_f16(a1h, bL0[1][i], acc, 0, 0, 0);
                acc = __builtin_amdgcn_mfma_f32_16x16x32_f16(a1l, bL0[1][i], acc, 0, 0, 0);
                acc = __builtin_amdgcn_mfma_f32_16x16x32_f16(axh, bL0[2][i], acc, 0, 0, 0);
                acc = __builtin_amdgcn_mfma_f32_16x16x32_f16(axl, bL0[2][i], acc, 0, 0, 0);
                #pragma unroll
                for (int r = 0; r < 4; ++r)
                    gl[(q * 4 + r) * GS + 64 * w + 16 * i + l15] = acc[r];
            }
        }
        __syncthreads();

        // ======== Phase B: layer-0 elementwise update ========
        #pragma unroll
        for (int k = 0; k < 4; ++k) {
            const int b    = w + 4 * k;
            const int base = b * GS + lane;
            float i_ = sigf (gl[base]       + bu0[0]);
            float f_ = sigf (gl[base + 64]  + bu0[1]);
            float g_ = tanh_(gl[base + 128] + bu0[2]);
            float o_ = sigf (gl[base + 192] + bu0[3]);
            float c  = f_ * c0r[k] + i_ * g_;
            c0r[k] = c;
            float h  = o_ * tanh_(c);
            f16 hh = (f16)h;
            Ahi[b * AS + lane] = hh;
            Alo[b * AS + lane] = (f16)(h - (float)hh);
        }
        __syncthreads();

        // ======== Phase C: layer-1 MFMA: gates = [h0_new | h1] @ B_L1 ========
        {
            f16x8 a0h = *(const f16x8*)&Ahi[arow + 0  + koff];
            f16x8 a0l = *(const f16x8*)&Alo[arow + 0  + koff];
            f16x8 a1h = *(const f16x8*)&Ahi[arow + 32 + koff];
            f16x8 a1l = *(const f16x8*)&Alo[arow + 32 + koff];
            f16x8 a2h = *(const f16x8*)&Ahi[arow + 64 + koff];
            f16x8 a2l = *(const f16x8*)&Alo[arow + 64 + koff];
            f16x8 a3h = *(const f16x8*)&Ahi[arow + 96 + koff];
            f16x8 a3l = *(const f16x8*)&Alo[arow + 96 + koff];
            #pragma unroll
            for (int i = 0; i < 4; ++i) {
                f32x4 acc = {0.f, 0.f, 0.f, 0.f};
                acc = __builtin_amdgcn_mfma_f32_16x16x32_f16(a0h, bL1[0][i], acc, 0, 0, 0);
                acc = __builtin_amdgcn_mfma_f32_16x16x32_f16(a0l, bL1[0][i], acc, 0, 0, 0);
                acc = __builtin_amdgcn_mfma_f32_16x16x32_f16(a1h, bL1[1][i], acc, 0, 0, 0);
                acc = __builtin_amdgcn_mfma_f32_16x16x32_f16(a1l, bL1[1][i], acc, 0, 0, 0);
                acc = __builtin_amdgcn_mfma_f32_16x16x32_f16(a2h, bL1[2][i], acc, 0, 0, 0);
                acc = __builtin_amdgcn_mfma_f32_16x16x32_f16(a2l, bL1[2][i], acc, 0, 0, 0);
                acc = __builtin_amdgcn_mfma_f32_16x16x32_f16(a3h, bL1[3][i], acc, 0, 0, 0);
                acc = __builtin_amdgcn_mfma_f32_16x16x32_f16(a3l, bL1[3][i], acc, 0, 0, 0);
                #pragma unroll
                for (int r = 0; r < 4; ++r)
                    gl[(q * 4 + r) * GS + 64 * w + 16 * i + l15] = acc[r];
            }
        }
        __syncthreads();

        // ======== Phase D: layer-1 elementwise update (+x store for next step) ========
        #pragma unroll
        for (int k = 0; k < 4; ++k) {
            const int b    = w + 4 * k;
            const int base = b * GS + lane;
            float i_ = sigf (gl[base]       + bu1[0]);
            float f_ = sigf (gl[base + 64]  + bu1[1]);
            float g_ = tanh_(gl[base + 128] + bu1[2]);
            float o_ = sigf (gl[base + 192] + bu1[3]);
            float c  = f_ * c1r[k] + i_ * g_;
            c1r[k] = c;
            float h  = o_ * tanh_(c);
            f16 hh = (f16)h;
            Ahi[b * AS + 64 + lane] = hh;
            Alo[b * AS + 64 + lane] = (f16)(h - (float)hh);
            if (tt == TT - 1) gl[base] = h;   // stash fp32 h1_last for the FC epilogue
        }
        if (loader) {
            f16 xh = (f16)xpre;
            Ahi[xb * AS + 128 + xf] = xh;
            Alo[xb * AS + 128 + xf] = (f16)(xpre - (float)xh);
        }
        __syncthreads();
    }

    // ======== FC epilogue: out = h1_last @ Wfc^T + bfc ========
    if (t < NB * OUTD) {
        const int b = t / OUTD;
        const int o = t - b * OUTD;
        float a = bfc[o];
        #pragma unroll
        for (int j = 0; j < H; ++j)
            a += Wfc[o * H + j] * gl[b * GS + j];
        out[(size_t)(b0 + b) * OUTD + o] = a;
    }
}

extern "C" void kernel_launch(void* const* d_in, const int* in_sizes, int n_in,
                              void* d_out, int out_size, void* d_ws, size_t ws_size,
                              hipStream_t stream) {
    const float* x    = (const float*)d_in[0];
    const float* Wih0 = (const float*)d_in[1];
    const float* Whh0 = (const float*)d_in[2];
    const float* bih0 = (const float*)d_in[3];
    const float* bhh0 = (const float*)d_in[4];
    const float* Wih1 = (const float*)d_in[5];
    const float* Whh1 = (const float*)d_in[6];
    const float* bih1 = (const float*)d_in[7];
    const float* bhh1 = (const float*)d_in[8];
    const float* Wfc  = (const float*)d_in[9];
    const float* bfc  = (const float*)d_in[10];

    dim3 grid(BTOT / NB);   // 256 blocks, 1 per CU
    dim3 block(256);
    lstm_mfma<<<grid, block, 0, stream>>>(x, Wih0, Whh0, bih0, bhh0,
                                          Wih1, Whh1, bih1, bhh1,
                                          Wfc, bfc, (float*)d_out);
}

// Round 3
// 1144.998 us; speedup vs baseline: 4.0776x; 1.2742x over previous
//
#include <hip/hip_runtime.h>

#define H    64
#define G    256
#define TT   512
#define NB   16
#define OUTD 3
#define BTOT 4096
#define INF  6

typedef _Float16 f16;
typedef _Float16 f16x8 __attribute__((ext_vector_type(8)));
typedef float    f32x4 __attribute__((ext_vector_type(4)));

// A-plane row stride (f16 elems): cols 0-63 h0 | 64-127 h1 | 128-135 x | pad
#define AS 168

__device__ __forceinline__ float sigf(float v)  { return 1.0f / (1.0f + __expf(-v)); }
__device__ __forceinline__ float tanh_(float v) { return 1.0f - 2.0f / (1.0f + __expf(2.0f * v)); }

__launch_bounds__(256, 1)
__global__ void lstm_mfma(const float* __restrict__ x,
                          const float* __restrict__ Wih0, const float* __restrict__ Whh0,
                          const float* __restrict__ bih0, const float* __restrict__ bhh0,
                          const float* __restrict__ Wih1, const float* __restrict__ Whh1,
                          const float* __restrict__ bih1, const float* __restrict__ bhh1,
                          const float* __restrict__ Wfc,  const float* __restrict__ bfc,
                          float* __restrict__ out)
{
    // double-buffered hi/lo A-planes (h0 | h1 | x), + fp32 last-h for the FC tail
    __shared__ __align__(16) f16   Ahi[2][NB * AS];
    __shared__ __align__(16) f16   Alo[2][NB * AS];
    __shared__ float hfin[NB][H + 1];

    const int t    = threadIdx.x;
    const int w    = t >> 6;        // wave: owns hidden cols j in [16w, 16w+16)
    const int l15  = t & 15;
    const int q    = (t >> 4) & 3;
    const int b0   = blockIdx.x * NB;
    const int jj   = 16 * w + l15;  // hidden column this thread owns (all 4 gates)

    // ---- weight B-fragments in registers: tile for gate g covers cols 64g+[16w,16w+16) ----
    f16x8 wh0[2][4];   // [kt][gate]  Whh0, K=64
    f16x8 wx0[4];      // [gate]      Wih0 x-tile (k<6 valid on q==0)
    f16x8 wi1[2][4];   // Wih1 (input = h0_new)
    f16x8 wh1[2][4];   // Whh1 (recurrent h1)
    #pragma unroll
    for (int g = 0; g < 4; ++g) {
        const int n = 64 * g + jj;
        #pragma unroll
        for (int kt = 0; kt < 2; ++kt) {
            f16x8 v0, v1, v2;
            #pragma unroll
            for (int j = 0; j < 8; ++j) {
                const int k = kt * 32 + q * 8 + j;
                v0[j] = (f16)Whh0[n * H + k];
                v1[j] = (f16)Wih1[n * H + k];
                v2[j] = (f16)Whh1[n * H + k];
            }
            wh0[kt][g] = v0; wi1[kt][g] = v1; wh1[kt][g] = v2;
        }
        f16x8 vx;
        #pragma unroll
        for (int j = 0; j < 8; ++j)
            vx[j] = (q == 0 && j < INF) ? (f16)Wih0[n * INF + j] : (f16)0.0f;
        wx0[g] = vx;
    }

    // per-thread biases (column jj, one per gate type)
    float bu0[4], bu1[4];
    #pragma unroll
    for (int g = 0; g < 4; ++g) {
        bu0[g] = bih0[64 * g + jj] + bhh0[64 * g + jj];
        bu1[g] = bih1[64 * g + jj] + bhh1[64 * g + jj];
    }

    // cell state: thread owns (b = q*4+r, j = jj)
    float c0r[4] = {0.f, 0.f, 0.f, 0.f};
    float c1r[4] = {0.f, 0.f, 0.f, 0.f};

    // ---- zero both A-plane buffers ----
    for (int idx = t; idx < 2 * NB * AS; idx += 256) {
        Ahi[0][idx] = (f16)0.0f;
        Alo[0][idx] = (f16)0.0f;
    }
    // x(0) into buffer 0
    const bool loader = (t < NB * INF);
    const int  xb = t / INF;
    const int  xf = t - xb * INF;
    if (loader) {
        float v = x[((size_t)(b0 + xb) * TT) * INF + xf];
        f16 vh = (f16)v;
        Ahi[0][xb * AS + 128 + xf] = vh;
        Alo[0][xb * AS + 128 + xf] = (f16)(v - (float)vh);
    }
    float xpre = 0.0f;
    __syncthreads();

    const int ar = l15 * AS;
    const int ko = q * 8;

    for (int tt = 0; tt < TT; ++tt) {
        const int p = tt & 1;
        const f16* __restrict__ AH = Ahi[p];     // read buffer (state of tt-1, x of tt)
        const f16* __restrict__ AL = Alo[p];
        f16* __restrict__ BH = Ahi[p ^ 1];       // write buffer (state of tt, x of tt+1)
        f16* __restrict__ BL = Alo[p ^ 1];

        // global x prefetch (consumed at end of step)
        if (loader) {
            const int tn = (tt + 1 < TT) ? (tt + 1) : (TT - 1);
            xpre = x[((size_t)(b0 + xb) * TT + tn) * INF + xf];
        }

        // ---- A-fragment loads: all of L0's operands + L1's h1 operands (buf p is stable) ----
        f16x8 a0h = *(const f16x8*)&AH[ar + 0   + ko];   // h0 k-tile 0
        f16x8 a0l = *(const f16x8*)&AL[ar + 0   + ko];
        f16x8 a1h = *(const f16x8*)&AH[ar + 32  + ko];   // h0 k-tile 1
        f16x8 a1l = *(const f16x8*)&AL[ar + 32  + ko];
        f16x8 axh = *(const f16x8*)&AH[ar + 128 + ko];   // x
        f16x8 axl = *(const f16x8*)&AL[ar + 128 + ko];
        f16x8 r0h = *(const f16x8*)&AH[ar + 64  + ko];   // h1 k-tile 0 (for L1)
        f16x8 r0l = *(const f16x8*)&AL[ar + 64  + ko];
        f16x8 r1h = *(const f16x8*)&AH[ar + 96  + ko];   // h1 k-tile 1 (for L1)
        f16x8 r1l = *(const f16x8*)&AL[ar + 96  + ko];

        // ---- L0 MFMA: per gate g, acc[r] = gate_g[b=q*4+r][jj] ----
        f32x4 accA[4];
        #pragma unroll
        for (int g = 0; g < 4; ++g) {
            f32x4 acc = {0.f, 0.f, 0.f, 0.f};
            acc = __builtin_amdgcn_mfma_f32_16x16x32_f16(a0h, wh0[0][g], acc, 0, 0, 0);
            acc = __builtin_amdgcn_mfma_f32_16x16x32_f16(a0l, wh0[0][g], acc, 0, 0, 0);
            acc = __builtin_amdgcn_mfma_f32_16x16x32_f16(a1h, wh0[1][g], acc, 0, 0, 0);
            acc = __builtin_amdgcn_mfma_f32_16x16x32_f16(a1l, wh0[1][g], acc, 0, 0, 0);
            acc = __builtin_amdgcn_mfma_f32_16x16x32_f16(axh, wx0[g],    acc, 0, 0, 0);
            acc = __builtin_amdgcn_mfma_f32_16x16x32_f16(axl, wx0[g],    acc, 0, 0, 0);
            accA[g] = acc;
        }

        // ---- L0 activation, fully in-register; write h0(tt) to buf p^1 ----
        #pragma unroll
        for (int r = 0; r < 4; ++r) {
            float i_ = sigf (accA[0][r] + bu0[0]);
            float f_ = sigf (accA[1][r] + bu0[1]);
            float g_ = tanh_(accA[2][r] + bu0[2]);
            float o_ = sigf (accA[3][r] + bu0[3]);
            float c  = f_ * c0r[r] + i_ * g_;
            c0r[r] = c;
            float h  = o_ * tanh_(c);
            f16 hh = (f16)h;
            const int addr = (q * 4 + r) * AS + jj;
            BH[addr] = hh;
            BL[addr] = (f16)(h - (float)hh);
        }
        __syncthreads();   // h0(tt) visible

        // ---- L1 MFMA: A = [h0_new (buf p^1) | h1 (preloaded from buf p)] ----
        f16x8 n0h = *(const f16x8*)&BH[ar + 0  + ko];
        f16x8 n0l = *(const f16x8*)&BL[ar + 0  + ko];
        f16x8 n1h = *(const f16x8*)&BH[ar + 32 + ko];
        f16x8 n1l = *(const f16x8*)&BL[ar + 32 + ko];
        f32x4 accB[4];
        #pragma unroll
        for (int g = 0; g < 4; ++g) {
            f32x4 acc = {0.f, 0.f, 0.f, 0.f};
            acc = __builtin_amdgcn_mfma_f32_16x16x32_f16(n0h, wi1[0][g], acc, 0, 0, 0);
            acc = __builtin_amdgcn_mfma_f32_16x16x32_f16(n0l, wi1[0][g], acc, 0, 0, 0);
            acc = __builtin_amdgcn_mfma_f32_16x16x32_f16(n1h, wi1[1][g], acc, 0, 0, 0);
            acc = __builtin_amdgcn_mfma_f32_16x16x32_f16(n1l, wi1[1][g], acc, 0, 0, 0);
            acc = __builtin_amdgcn_mfma_f32_16x16x32_f16(r0h, wh1[0][g], acc, 0, 0, 0);
            acc = __builtin_amdgcn_mfma_f32_16x16x32_f16(r0l, wh1[0][g], acc, 0, 0, 0);
            acc = __builtin_amdgcn_mfma_f32_16x16x32_f16(r1h, wh1[1][g], acc, 0, 0, 0);
            acc = __builtin_amdgcn_mfma_f32_16x16x32_f16(r1l, wh1[1][g], acc, 0, 0, 0);
            accB[g] = acc;
        }

        // ---- L1 activation; write h1(tt) + x(tt+1) to buf p^1 ----
        #pragma unroll
        for (int r = 0; r < 4; ++r) {
            float i_ = sigf (accB[0][r] + bu1[0]);
            float f_ = sigf (accB[1][r] + bu1[1]);
            float g_ = tanh_(accB[2][r] + bu1[2]);
            float o_ = sigf (accB[3][r] + bu1[3]);
            float c  = f_ * c1r[r] + i_ * g_;
            c1r[r] = c;
            float h  = o_ * tanh_(c);
            f16 hh = (f16)h;
            const int addr = (q * 4 + r) * AS + 64 + jj;
            BH[addr] = hh;
            BL[addr] = (f16)(h - (float)hh);
            if (tt == TT - 1) hfin[q * 4 + r][jj] = h;
        }
        if (loader) {
            f16 xh = (f16)xpre;
            BH[xb * AS + 128 + xf] = xh;
            BL[xb * AS + 128 + xf] = (f16)(xpre - (float)xh);
        }
        __syncthreads();   // h1(tt), x(tt+1) visible
    }

    // ---- FC epilogue ----
    if (t < NB * OUTD) {
        const int b = t / OUTD;
        const int o = t - b * OUTD;
        float a = bfc[o];
        #pragma unroll
        for (int j = 0; j < H; ++j)
            a += Wfc[o * H + j] * hfin[b][j];
        out[(size_t)(b0 + b) * OUTD + o] = a;
    }
}

extern "C" void kernel_launch(void* const* d_in, const int* in_sizes, int n_in,
                              void* d_out, int out_size, void* d_ws, size_t ws_size,
                              hipStream_t stream) {
    const float* x    = (const float*)d_in[0];
    const float* Wih0 = (const float*)d_in[1];
    const float* Whh0 = (const float*)d_in[2];
    const float* bih0 = (const float*)d_in[3];
    const float* bhh0 = (const float*)d_in[4];
    const float* Wih1 = (const float*)d_in[5];
    const float* Whh1 = (const float*)d_in[6];
    const float* bih1 = (const float*)d_in[7];
    const float* bhh1 = (const float*)d_in[8];
    const float* Wfc  = (const float*)d_in[9];
    const float* bfc  = (const float*)d_in[10];

    dim3 grid(BTOT / NB);   // 256 blocks, 1 per CU
    dim3 block(256);
    lstm_mfma<<<grid, block, 0, stream>>>(x, Wih0, Whh0, bih0, bhh0,
                                          Wih1, Whh1, bih1, bhh1,
                                          Wfc, bfc, (float*)d_out);
}

// Round 4
// 762.438 us; speedup vs baseline: 6.1236x; 1.5018x over previous
//
#include <hip/hip_runtime.h>

#define H    64
#define G    256
#define TT   512
#define NB   16
#define OUTD 3
#define BTOT 4096
#define INF  6

typedef _Float16 f16;
typedef _Float16 f16x8 __attribute__((ext_vector_type(8)));
typedef float    f32x4 __attribute__((ext_vector_type(4)));

// A-plane row stride (f16 elems): cols 0-63 h0 | 64-127 h1 | 128-135 x | pad
#define AS 168

#define LOG2E 1.44269504088896340736f

// sigmoid(v) where s = v*log2e already folded into weights:  1/(1+2^-s)
__device__ __forceinline__ float sig2(float s) {
    return __builtin_amdgcn_rcpf(1.0f + __builtin_amdgcn_exp2f(-s));
}
// tanh(v) where s = v*2*log2e already folded:  1 - 2/(1+2^s)
__device__ __forceinline__ float tanh2(float s) {
    return 1.0f - 2.0f * __builtin_amdgcn_rcpf(1.0f + __builtin_amdgcn_exp2f(s));
}
// tanh of an unscaled value (for tanh(c))
__device__ __forceinline__ float tanh_u(float v) {
    return 1.0f - 2.0f * __builtin_amdgcn_rcpf(1.0f + __builtin_amdgcn_exp2f(v * (2.0f * LOG2E)));
}

__launch_bounds__(256, 1)
__global__ void lstm_mfma(const float* __restrict__ x,
                          const float* __restrict__ Wih0, const float* __restrict__ Whh0,
                          const float* __restrict__ bih0, const float* __restrict__ bhh0,
                          const float* __restrict__ Wih1, const float* __restrict__ Whh1,
                          const float* __restrict__ bih1, const float* __restrict__ bhh1,
                          const float* __restrict__ Wfc,  const float* __restrict__ bfc,
                          float* __restrict__ out)
{
    __shared__ __align__(16) f16   Ahi[2][NB * AS];
    __shared__ __align__(16) f16   Alo[2][NB * AS];
    __shared__ float hfin[NB][H + 1];

    const int t    = threadIdx.x;
    const int w    = t >> 6;
    const int l15  = t & 15;
    const int q    = (t >> 4) & 3;
    const int b0   = blockIdx.x * NB;
    const int jj   = 16 * w + l15;   // hidden column this thread owns (all 4 gates)

    // ---- weight B-fragments in registers, pre-scaled for exp2-based activations ----
    // gates i,f,o (g-index 0,1,3): x log2e ; gate g (g-index 2): x 2*log2e
    f16x8 wh0[2][4];
    f16x8 wx0[4];
    f16x8 wi1[2][4];
    f16x8 wh1[2][4];
    #pragma unroll
    for (int g = 0; g < 4; ++g) {
        const float sc = (g == 2) ? (2.0f * LOG2E) : LOG2E;
        const int n = 64 * g + jj;
        #pragma unroll
        for (int kt = 0; kt < 2; ++kt) {
            f16x8 v0, v1, v2;
            #pragma unroll
            for (int j = 0; j < 8; ++j) {
                const int k = kt * 32 + q * 8 + j;
                v0[j] = (f16)(Whh0[n * H + k] * sc);
                v1[j] = (f16)(Wih1[n * H + k] * sc);
                v2[j] = (f16)(Whh1[n * H + k] * sc);
            }
            wh0[kt][g] = v0; wi1[kt][g] = v1; wh1[kt][g] = v2;
        }
        f16x8 vx;
        #pragma unroll
        for (int j = 0; j < 8; ++j)
            vx[j] = (q == 0 && j < INF) ? (f16)(Wih0[n * INF + j] * sc) : (f16)0.0f;
        wx0[g] = vx;
    }

    // per-thread biases, same pre-scale
    float bu0[4], bu1[4];
    #pragma unroll
    for (int g = 0; g < 4; ++g) {
        const float sc = (g == 2) ? (2.0f * LOG2E) : LOG2E;
        bu0[g] = (bih0[64 * g + jj] + bhh0[64 * g + jj]) * sc;
        bu1[g] = (bih1[64 * g + jj] + bhh1[64 * g + jj]) * sc;
    }

    // cell state: thread owns (b = q*4+r, j = jj)
    float c0r[4] = {0.f, 0.f, 0.f, 0.f};
    float c1r[4] = {0.f, 0.f, 0.f, 0.f};

    // ---- zero both A-plane buffers ----
    for (int idx = t; idx < 2 * NB * AS; idx += 256) {
        Ahi[0][idx] = (f16)0.0f;
        Alo[0][idx] = (f16)0.0f;
    }
    const bool loader = (t < NB * INF);
    const int  xb = t / INF;
    const int  xf = t - xb * INF;
    if (loader) {
        float v = x[((size_t)(b0 + xb) * TT) * INF + xf];
        f16 vh = (f16)v;
        Ahi[0][xb * AS + 128 + xf] = vh;
        Alo[0][xb * AS + 128 + xf] = (f16)(v - (float)vh);
    }
    float xpre = 0.0f;
    __syncthreads();

    const int ar = l15 * AS;
    const int ko = q * 8;

    // ---- one LSTM time-step: reads state from A planes, writes to B planes ----
    auto step = [&](const f16* __restrict__ AH, const f16* __restrict__ AL,
                    f16* __restrict__ BH, f16* __restrict__ BL, int tt) {
        // global x prefetch (consumed at end of step)
        if (loader) {
            const int tn = (tt + 1 < TT) ? (tt + 1) : (TT - 1);
            xpre = x[((size_t)(b0 + xb) * TT + tn) * INF + xf];
        }

        // A-fragment loads from the stable read buffer
        f16x8 a0h = *(const f16x8*)&AH[ar + 0   + ko];   // h0 kt0
        f16x8 a0l = *(const f16x8*)&AL[ar + 0   + ko];
        f16x8 a1h = *(const f16x8*)&AH[ar + 32  + ko];   // h0 kt1
        f16x8 a1l = *(const f16x8*)&AL[ar + 32  + ko];
        f16x8 axh = *(const f16x8*)&AH[ar + 128 + ko];   // x
        f16x8 axl = *(const f16x8*)&AL[ar + 128 + ko];
        f16x8 r0h = *(const f16x8*)&AH[ar + 64  + ko];   // h1 kt0 (for L1)
        f16x8 r0l = *(const f16x8*)&AL[ar + 64  + ko];
        f16x8 r1h = *(const f16x8*)&AH[ar + 96  + ko];   // h1 kt1 (for L1)
        f16x8 r1l = *(const f16x8*)&AL[ar + 96  + ko];

        // L0 MFMA
        f32x4 accA[4];
        #pragma unroll
        for (int g = 0; g < 4; ++g) {
            f32x4 acc = {0.f, 0.f, 0.f, 0.f};
            acc = __builtin_amdgcn_mfma_f32_16x16x32_f16(a0h, wh0[0][g], acc, 0, 0, 0);
            acc = __builtin_amdgcn_mfma_f32_16x16x32_f16(a0l, wh0[0][g], acc, 0, 0, 0);
            acc = __builtin_amdgcn_mfma_f32_16x16x32_f16(a1h, wh0[1][g], acc, 0, 0, 0);
            acc = __builtin_amdgcn_mfma_f32_16x16x32_f16(a1l, wh0[1][g], acc, 0, 0, 0);
            acc = __builtin_amdgcn_mfma_f32_16x16x32_f16(axh, wx0[g],    acc, 0, 0, 0);
            acc = __builtin_amdgcn_mfma_f32_16x16x32_f16(axl, wx0[g],    acc, 0, 0, 0);
            accA[g] = acc;
        }

        // L0 activation (in-register), write h0(tt) to B planes
        #pragma unroll
        for (int r = 0; r < 4; ++r) {
            float i_ = sig2 (accA[0][r] + bu0[0]);
            float f_ = sig2 (accA[1][r] + bu0[1]);
            float g_ = tanh2(accA[2][r] + bu0[2]);
            float o_ = sig2 (accA[3][r] + bu0[3]);
            float c  = f_ * c0r[r] + i_ * g_;
            c0r[r] = c;
            float h  = o_ * tanh_u(c);
            f16 hh = (f16)h;
            const int addr = (q * 4 + r) * AS + jj;
            BH[addr] = hh;
            BL[addr] = (f16)(h - (float)hh);
        }
        __syncthreads();   // h0(tt) visible

        // L1 MFMA: A = [h0_new | h1(prev)]
        f16x8 n0h = *(const f16x8*)&BH[ar + 0  + ko];
        f16x8 n0l = *(const f16x8*)&BL[ar + 0  + ko];
        f16x8 n1h = *(const f16x8*)&BH[ar + 32 + ko];
        f16x8 n1l = *(const f16x8*)&BL[ar + 32 + ko];
        f32x4 accB[4];
        #pragma unroll
        for (int g = 0; g < 4; ++g) {
            f32x4 acc = {0.f, 0.f, 0.f, 0.f};
            acc = __builtin_amdgcn_mfma_f32_16x16x32_f16(n0h, wi1[0][g], acc, 0, 0, 0);
            acc = __builtin_amdgcn_mfma_f32_16x16x32_f16(n0l, wi1[0][g], acc, 0, 0, 0);
            acc = __builtin_amdgcn_mfma_f32_16x16x32_f16(n1h, wi1[1][g], acc, 0, 0, 0);
            acc = __builtin_amdgcn_mfma_f32_16x16x32_f16(n1l, wi1[1][g], acc, 0, 0, 0);
            acc = __builtin_amdgcn_mfma_f32_16x16x32_f16(r0h, wh1[0][g], acc, 0, 0, 0);
            acc = __builtin_amdgcn_mfma_f32_16x16x32_f16(r0l, wh1[0][g], acc, 0, 0, 0);
            acc = __builtin_amdgcn_mfma_f32_16x16x32_f16(r1h, wh1[1][g], acc, 0, 0, 0);
            acc = __builtin_amdgcn_mfma_f32_16x16x32_f16(r1l, wh1[1][g], acc, 0, 0, 0);
            accB[g] = acc;
        }

        // L1 activation; write h1(tt) + x(tt+1)
        #pragma unroll
        for (int r = 0; r < 4; ++r) {
            float i_ = sig2 (accB[0][r] + bu1[0]);
            float f_ = sig2 (accB[1][r] + bu1[1]);
            float g_ = tanh2(accB[2][r] + bu1[2]);
            float o_ = sig2 (accB[3][r] + bu1[3]);
            float c  = f_ * c1r[r] + i_ * g_;
            c1r[r] = c;
            float h  = o_ * tanh_u(c);
            f16 hh = (f16)h;
            const int addr = (q * 4 + r) * AS + 64 + jj;
            BH[addr] = hh;
            BL[addr] = (f16)(h - (float)hh);
            if (tt == TT - 1) hfin[q * 4 + r][jj] = h;
        }
        if (loader) {
            f16 xh = (f16)xpre;
            BH[xb * AS + 128 + xf] = xh;
            BL[xb * AS + 128 + xf] = (f16)(xpre - (float)xh);
        }
        __syncthreads();   // h1(tt), x(tt+1) visible
    };

    // explicit x2 unroll: compile-time buffer pointers (no p^1 arithmetic)
    for (int tt = 0; tt < TT; tt += 2) {
        step(Ahi[0], Alo[0], Ahi[1], Alo[1], tt);
        step(Ahi[1], Alo[1], Ahi[0], Alo[0], tt + 1);
    }

    // ---- FC epilogue ----
    if (t < NB * OUTD) {
        const int b = t / OUTD;
        const int o = t - b * OUTD;
        float a = bfc[o];
        #pragma unroll
        for (int j = 0; j < H; ++j)
            a += Wfc[o * H + j] * hfin[b][j];
        out[(size_t)(b0 + b) * OUTD + o] = a;
    }
}

extern "C" void kernel_launch(void* const* d_in, const int* in_sizes, int n_in,
                              void* d_out, int out_size, void* d_ws, size_t ws_size,
                              hipStream_t stream) {
    const float* x    = (const float*)d_in[0];
    const float* Wih0 = (const float*)d_in[1];
    const float* Whh0 = (const float*)d_in[2];
    const float* bih0 = (const float*)d_in[3];
    const float* bhh0 = (const float*)d_in[4];
    const float* Wih1 = (const float*)d_in[5];
    const float* Whh1 = (const float*)d_in[6];
    const float* bih1 = (const float*)d_in[7];
    const float* bhh1 = (const float*)d_in[8];
    const float* Wfc  = (const float*)d_in[9];
    const float* bfc  = (const float*)d_in[10];

    dim3 grid(BTOT / NB);   // 256 blocks, 1 per CU
    dim3 block(256);
    lstm_mfma<<<grid, block, 0, stream>>>(x, Wih0, Whh0, bih0, bhh0,
                                          Wih1, Whh1, bih1, bhh1,
                                          Wfc, bfc, (float*)d_out);
}

// Round 5
// 631.690 us; speedup vs baseline: 7.3911x; 1.2070x over previous
//
#include <hip/hip_runtime.h>

#define H    64
#define TT   512
#define NB   16
#define OUTD 3
#define BTOT 4096
#define INF  6

typedef _Float16 f16;
typedef _Float16 f16x8 __attribute__((ext_vector_type(8)));
typedef float    f32x4 __attribute__((ext_vector_type(4)));

// plane row stride (f16 elems): cols 0-63 h0 | 64-127 h1 | 128-135 x | pad
#define AS 168

#define LOG2E 1.44269504088896340736f

__device__ __forceinline__ float sig2(float s) {      // sigmoid, log2e pre-folded
    return __builtin_amdgcn_rcpf(1.0f + __builtin_amdgcn_exp2f(-s));
}
__device__ __forceinline__ float tanh2(float s) {     // tanh, 2*log2e pre-folded
    return 1.0f - 2.0f * __builtin_amdgcn_rcpf(1.0f + __builtin_amdgcn_exp2f(s));
}
__device__ __forceinline__ float tanh_u(float v) {    // tanh of unscaled value
    return 1.0f - 2.0f * __builtin_amdgcn_rcpf(1.0f + __builtin_amdgcn_exp2f(v * (2.0f * LOG2E)));
}

// Wave-specialized layer pipeline:
//   waves 0-3 (role 0): layer-0, compute h0(s) at slot s          (s = 0..TT-1)
//   waves 4-7 (role 1): layer-1, compute h1(s-1) at slot s        (s = 1..TT)
// One barrier per slot. h0(s) lives in plane s&1 cols 0-63; h1(s-1) in plane
// (s-1)&1 cols 64-127; x(s) in plane s&1 cols 128+. All same-slot read/write
// address ranges are disjoint; the slot barrier orders producer->consumer.
__launch_bounds__(512, 2)
__global__ void lstm_ws(const float* __restrict__ x,
                        const float* __restrict__ Wih0, const float* __restrict__ Whh0,
                        const float* __restrict__ bih0, const float* __restrict__ bhh0,
                        const float* __restrict__ Wih1, const float* __restrict__ Whh1,
                        const float* __restrict__ bih1, const float* __restrict__ bhh1,
                        const float* __restrict__ Wfc,  const float* __restrict__ bfc,
                        float* __restrict__ out)
{
    __shared__ __align__(16) f16   Phi[2][NB * AS];
    __shared__ __align__(16) f16   Plo[2][NB * AS];
    __shared__ float hfin[NB][H + 1];

    const int t    = threadIdx.x;
    const int u    = t & 255;
    const int role = t >> 8;
    const int wv   = u >> 6;
    const int l15  = u & 15;
    const int q    = (u >> 4) & 3;
    const int jj   = 16 * wv + l15;   // hidden column this thread owns (all 4 gates)
    const int b0   = blockIdx.x * NB;
    const int ar   = l15 * AS;
    const int ko   = q * 8;

    // ---- zero both planes ----
    {
        f16* ph = &Phi[0][0]; f16* pl = &Plo[0][0];
        for (int idx = t; idx < 2 * NB * AS; idx += 512) {
            ph[idx] = (f16)0.0f; pl[idx] = (f16)0.0f;
        }
    }
    __syncthreads();   // zeroing complete before x(0) store (avoid init race)

    const bool loader = (role == 0) && (u < NB * INF);
    const int  xb = u / INF;
    const int  xf = u - xb * INF;
    if (loader) {
        float v = x[((size_t)(b0 + xb) * TT) * INF + xf];
        f16 vh = (f16)v;
        Phi[0][xb * AS + 128 + xf] = vh;
        Plo[0][xb * AS + 128 + xf] = (f16)(v - (float)vh);
    }
    __syncthreads();

    if (role == 0) {
        // ================= LAYER-0 waves =================
        f16x8 wh0[2][4];   // Whh0 fragments, pre-scaled
        f16x8 wx0[4];      // Wih0 x-tile (k<6 valid on q==0)
        float bu0[4];
        #pragma unroll
        for (int g = 0; g < 4; ++g) {
            const float sc = (g == 2) ? (2.0f * LOG2E) : LOG2E;
            const int n = 64 * g + jj;
            #pragma unroll
            for (int kt = 0; kt < 2; ++kt) {
                f16x8 v;
                #pragma unroll
                for (int j = 0; j < 8; ++j)
                    v[j] = (f16)(Whh0[n * H + kt * 32 + q * 8 + j] * sc);
                wh0[kt][g] = v;
            }
            f16x8 vx;
            #pragma unroll
            for (int j = 0; j < 8; ++j)
                vx[j] = (q == 0 && j < INF) ? (f16)(Wih0[n * INF + j] * sc) : (f16)0.0f;
            wx0[g] = vx;
            bu0[g] = (bih0[64 * g + jj] + bhh0[64 * g + jj]) * sc;
        }
        float c0r[4] = {0.f, 0.f, 0.f, 0.f};
        float xpre = 0.0f;

        // AH/AL = plane p^1 (h0(s-1) read, x(s+1) write); BH/BL = plane p (x(s) read, h0(s) write)
        auto stepL0 = [&](f16* __restrict__ AH, f16* __restrict__ AL,
                          f16* __restrict__ BH, f16* __restrict__ BL, int s) {
            if (loader) {
                const int tn = (s + 1 < TT) ? (s + 1) : (TT - 1);
                xpre = x[((size_t)(b0 + xb) * TT + tn) * INF + xf];
            }
            f16x8 a0h = *(const f16x8*)&AH[ar + 0   + ko];
            f16x8 a0l = *(const f16x8*)&AL[ar + 0   + ko];
            f16x8 a1h = *(const f16x8*)&AH[ar + 32  + ko];
            f16x8 a1l = *(const f16x8*)&AL[ar + 32  + ko];
            f16x8 axh = *(const f16x8*)&BH[ar + 128 + ko];
            f16x8 axl = *(const f16x8*)&BL[ar + 128 + ko];
            f32x4 accA[4];
            #pragma unroll
            for (int g = 0; g < 4; ++g) {
                f32x4 acc = {0.f, 0.f, 0.f, 0.f};
                acc = __builtin_amdgcn_mfma_f32_16x16x32_f16(a0h, wh0[0][g], acc, 0, 0, 0);
                acc = __builtin_amdgcn_mfma_f32_16x16x32_f16(a0l, wh0[0][g], acc, 0, 0, 0);
                acc = __builtin_amdgcn_mfma_f32_16x16x32_f16(a1h, wh0[1][g], acc, 0, 0, 0);
                acc = __builtin_amdgcn_mfma_f32_16x16x32_f16(a1l, wh0[1][g], acc, 0, 0, 0);
                acc = __builtin_amdgcn_mfma_f32_16x16x32_f16(axh, wx0[g],    acc, 0, 0, 0);
                acc = __builtin_amdgcn_mfma_f32_16x16x32_f16(axl, wx0[g],    acc, 0, 0, 0);
                accA[g] = acc;
            }
            #pragma unroll
            for (int r = 0; r < 4; ++r) {
                float i_ = sig2 (accA[0][r] + bu0[0]);
                float f_ = sig2 (accA[1][r] + bu0[1]);
                float g_ = tanh2(accA[2][r] + bu0[2]);
                float o_ = sig2 (accA[3][r] + bu0[3]);
                float c  = f_ * c0r[r] + i_ * g_;
                c0r[r] = c;
                float h  = o_ * tanh_u(c);
                f16 hh = (f16)h;
                const int addr = (q * 4 + r) * AS + jj;
                BH[addr] = hh;
                BL[addr] = (f16)(h - (float)hh);
            }
            if (loader) {
                f16 xh = (f16)xpre;
                AH[xb * AS + 128 + xf] = xh;
                AL[xb * AS + 128 + xf] = (f16)(xpre - (float)xh);
            }
            __syncthreads();
        };

        for (int s = 0; s < TT; s += 2) {
            stepL0(Phi[1], Plo[1], Phi[0], Plo[0], s);
            stepL0(Phi[0], Plo[0], Phi[1], Plo[1], s + 1);
        }
        __syncthreads();   // slot TT (layer-1 finishes h1(TT-1))
    } else {
        // ================= LAYER-1 waves =================
        f16x8 wi1[2][4];   // Wih1 (input = h0)
        f16x8 wh1[2][4];   // Whh1 (recurrent h1)
        float bu1[4];
        #pragma unroll
        for (int g = 0; g < 4; ++g) {
            const float sc = (g == 2) ? (2.0f * LOG2E) : LOG2E;
            const int n = 64 * g + jj;
            #pragma unroll
            for (int kt = 0; kt < 2; ++kt) {
                f16x8 v1, v2;
                #pragma unroll
                for (int j = 0; j < 8; ++j) {
                    const int k = kt * 32 + q * 8 + j;
                    v1[j] = (f16)(Wih1[n * H + k] * sc);
                    v2[j] = (f16)(Whh1[n * H + k] * sc);
                }
                wi1[kt][g] = v1; wh1[kt][g] = v2;
            }
            bu1[g] = (bih1[64 * g + jj] + bhh1[64 * g + jj]) * sc;
        }
        float c1r[4] = {0.f, 0.f, 0.f, 0.f};

        __syncthreads();   // slot 0 (layer-0 produces h0(0))

        // AH/AL = plane p^1 (h0(s-1) read, h1(s-1) write); BH/BL = plane p (h1(s-2) read)
        auto stepL1 = [&](f16* __restrict__ AH, f16* __restrict__ AL,
                          f16* __restrict__ BH, f16* __restrict__ BL, int s) {
            f16x8 n0h = *(const f16x8*)&AH[ar + 0  + ko];
            f16x8 n0l = *(const f16x8*)&AL[ar + 0  + ko];
            f16x8 n1h = *(const f16x8*)&AH[ar + 32 + ko];
            f16x8 n1l = *(const f16x8*)&AL[ar + 32 + ko];
            f16x8 r0h = *(const f16x8*)&BH[ar + 64 + ko];
            f16x8 r0l = *(const f16x8*)&BL[ar + 64 + ko];
            f16x8 r1h = *(const f16x8*)&BH[ar + 96 + ko];
            f16x8 r1l = *(const f16x8*)&BL[ar + 96 + ko];
            f32x4 accB[4];
            #pragma unroll
            for (int g = 0; g < 4; ++g) {
                f32x4 acc = {0.f, 0.f, 0.f, 0.f};
                acc = __builtin_amdgcn_mfma_f32_16x16x32_f16(n0h, wi1[0][g], acc, 0, 0, 0);
                acc = __builtin_amdgcn_mfma_f32_16x16x32_f16(n0l, wi1[0][g], acc, 0, 0, 0);
                acc = __builtin_amdgcn_mfma_f32_16x16x32_f16(n1h, wi1[1][g], acc, 0, 0, 0);
                acc = __builtin_amdgcn_mfma_f32_16x16x32_f16(n1l, wi1[1][g], acc, 0, 0, 0);
                acc = __builtin_amdgcn_mfma_f32_16x16x32_f16(r0h, wh1[0][g], acc, 0, 0, 0);
                acc = __builtin_amdgcn_mfma_f32_16x16x32_f16(r0l, wh1[0][g], acc, 0, 0, 0);
                acc = __builtin_amdgcn_mfma_f32_16x16x32_f16(r1h, wh1[1][g], acc, 0, 0, 0);
                acc = __builtin_amdgcn_mfma_f32_16x16x32_f16(r1l, wh1[1][g], acc, 0, 0, 0);
                accB[g] = acc;
            }
            #pragma unroll
            for (int r = 0; r < 4; ++r) {
                float i_ = sig2 (accB[0][r] + bu1[0]);
                float f_ = sig2 (accB[1][r] + bu1[1]);
                float g_ = tanh2(accB[2][r] + bu1[2]);
                float o_ = sig2 (accB[3][r] + bu1[3]);
                float c  = f_ * c1r[r] + i_ * g_;
                c1r[r] = c;
                float h  = o_ * tanh_u(c);
                f16 hh = (f16)h;
                const int addr = (q * 4 + r) * AS + 64 + jj;
                AH[addr] = hh;
                AL[addr] = (f16)(h - (float)hh);
                if (s == TT) hfin[q * 4 + r][jj] = h;
            }
            __syncthreads();
        };

        for (int s = 1; s <= TT; s += 2) {
            stepL1(Phi[0], Plo[0], Phi[1], Plo[1], s);
            stepL1(Phi[1], Plo[1], Phi[0], Plo[0], s + 1);
        }
    }

    // ---- FC epilogue ----
    if (t < NB * OUTD) {
        const int b = t / OUTD;
        const int o = t - b * OUTD;
        float a = bfc[o];
        #pragma unroll
        for (int j = 0; j < H; ++j)
            a += Wfc[o * H + j] * hfin[b][j];
        out[(size_t)(b0 + b) * OUTD + o] = a;
    }
}

extern "C" void kernel_launch(void* const* d_in, const int* in_sizes, int n_in,
                              void* d_out, int out_size, void* d_ws, size_t ws_size,
                              hipStream_t stream) {
    const float* x    = (const float*)d_in[0];
    const float* Wih0 = (const float*)d_in[1];
    const float* Whh0 = (const float*)d_in[2];
    const float* bih0 = (const float*)d_in[3];
    const float* bhh0 = (const float*)d_in[4];
    const float* Wih1 = (const float*)d_in[5];
    const float* Whh1 = (const float*)d_in[6];
    const float* bih1 = (const float*)d_in[7];
    const float* bhh1 = (const float*)d_in[8];
    const float* Wfc  = (const float*)d_in[9];
    const float* bfc  = (const float*)d_in[10];

    dim3 grid(BTOT / NB);   // 256 blocks, 1 per CU; 8 waves = 2 waves/SIMD
    dim3 block(512);
    lstm_ws<<<grid, block, 0, stream>>>(x, Wih0, Whh0, bih0, bhh0,
                                        Wih1, Whh1, bih1, bhh1,
                                        Wfc, bfc, (float*)d_out);
}

// Round 6
// 461.491 us; speedup vs baseline: 10.1170x; 1.3688x over previous
//
#include <hip/hip_runtime.h>

#define H    64
#define TT   512
#define NB   16
#define OUTD 3
#define BTOT 4096
#define INF  6

typedef _Float16 f16;
typedef _Float16 f16x8 __attribute__((ext_vector_type(8)));
typedef float    f32x4 __attribute__((ext_vector_type(4)));

// plane row stride (f16 elems): cols 0-63 h0 | 64-127 h1 | 128-135 x | pad
#define AS 168

#define LOG2E 1.44269504088896340736f

__device__ __forceinline__ float sig2(float s) {      // sigmoid, log2e pre-folded
    return __builtin_amdgcn_rcpf(1.0f + __builtin_amdgcn_exp2f(-s));
}
__device__ __forceinline__ float tanh2(float s) {     // tanh, 2*log2e pre-folded
    return 1.0f - 2.0f * __builtin_amdgcn_rcpf(1.0f + __builtin_amdgcn_exp2f(s));
}
__device__ __forceinline__ float tanh_u(float v) {    // tanh of unscaled value
    return 1.0f - 2.0f * __builtin_amdgcn_rcpf(1.0f + __builtin_amdgcn_exp2f(v * (2.0f * LOG2E)));
}

// Wave-specialized layer pipeline (single-f16 state planes):
//   waves 0-3 (role 0): layer-0, compute h0(s) at slot s          (s = 0..TT-1)
//   waves 4-7 (role 1): layer-1, compute h1(s-1) at slot s        (s = 1..TT)
// One barrier per slot. h0(s) -> plane s&1 cols 0-63; h1(s-1) -> plane (s-1)&1
// cols 64-127; x(s) -> plane s&1 cols 128+. Same-slot ranges disjoint.
__launch_bounds__(512, 2)
__global__ void lstm_ws(const float* __restrict__ x,
                        const float* __restrict__ Wih0, const float* __restrict__ Whh0,
                        const float* __restrict__ bih0, const float* __restrict__ bhh0,
                        const float* __restrict__ Wih1, const float* __restrict__ Whh1,
                        const float* __restrict__ bih1, const float* __restrict__ bhh1,
                        const float* __restrict__ Wfc,  const float* __restrict__ bfc,
                        float* __restrict__ out)
{
    __shared__ __align__(16) f16 Phi[2][NB * AS];
    __shared__ float hfin[NB][H + 1];

    const int t    = threadIdx.x;
    const int u    = t & 255;
    const int role = t >> 8;
    const int wv   = u >> 6;
    const int l15  = u & 15;
    const int q    = (u >> 4) & 3;
    const int jj   = 16 * wv + l15;   // hidden column this thread owns (all 4 gates)
    const int b0   = blockIdx.x * NB;
    const int ar   = l15 * AS;
    const int ko   = q * 8;

    // ---- zero both planes ----
    {
        f16* ph = &Phi[0][0];
        for (int idx = t; idx < 2 * NB * AS; idx += 512) ph[idx] = (f16)0.0f;
    }
    __syncthreads();   // zeroing complete before x(0) store

    const bool loader = (role == 0) && (u < NB * INF);
    const int  xb = u / INF;
    const int  xf = u - xb * INF;
    if (loader)
        Phi[0][xb * AS + 128 + xf] = (f16)x[((size_t)(b0 + xb) * TT) * INF + xf];
    __syncthreads();

    if (role == 0) {
        // ================= LAYER-0 waves =================
        f16x8 wh0[2][4];   // Whh0 fragments, pre-scaled
        f16x8 wx0[4];      // Wih0 x-tile (k<6 valid on q==0)
        float bu0[4];
        #pragma unroll
        for (int g = 0; g < 4; ++g) {
            const float sc = (g == 2) ? (2.0f * LOG2E) : LOG2E;
            const int n = 64 * g + jj;
            #pragma unroll
            for (int kt = 0; kt < 2; ++kt) {
                f16x8 v;
                #pragma unroll
                for (int j = 0; j < 8; ++j)
                    v[j] = (f16)(Whh0[n * H + kt * 32 + q * 8 + j] * sc);
                wh0[kt][g] = v;
            }
            f16x8 vx;
            #pragma unroll
            for (int j = 0; j < 8; ++j)
                vx[j] = (q == 0 && j < INF) ? (f16)(Wih0[n * INF + j] * sc) : (f16)0.0f;
            wx0[g] = vx;
            bu0[g] = (bih0[64 * g + jj] + bhh0[64 * g + jj]) * sc;
        }
        float c0r[4] = {0.f, 0.f, 0.f, 0.f};
        float xpre = 0.0f;

        // AH = plane p^1 (h0(s-1) read, x(s+1) write); BH = plane p (x(s) read, h0(s) write)
        auto stepL0 = [&](f16* __restrict__ AH, f16* __restrict__ BH, int s) {
            if (loader) {
                const int tn = (s + 1 < TT) ? (s + 1) : (TT - 1);
                xpre = x[((size_t)(b0 + xb) * TT + tn) * INF + xf];
            }
            f16x8 a0 = *(const f16x8*)&AH[ar + 0   + ko];
            f16x8 a1 = *(const f16x8*)&AH[ar + 32  + ko];
            f16x8 ax = *(const f16x8*)&BH[ar + 128 + ko];
            f32x4 accA[4];
            #pragma unroll
            for (int g = 0; g < 4; ++g) {
                f32x4 acc = {bu0[g], bu0[g], bu0[g], bu0[g]};   // bias pre-loaded
                acc = __builtin_amdgcn_mfma_f32_16x16x32_f16(a0, wh0[0][g], acc, 0, 0, 0);
                acc = __builtin_amdgcn_mfma_f32_16x16x32_f16(a1, wh0[1][g], acc, 0, 0, 0);
                acc = __builtin_amdgcn_mfma_f32_16x16x32_f16(ax, wx0[g],    acc, 0, 0, 0);
                accA[g] = acc;
            }
            #pragma unroll
            for (int r = 0; r < 4; ++r) {
                float i_ = sig2 (accA[0][r]);
                float f_ = sig2 (accA[1][r]);
                float g_ = tanh2(accA[2][r]);
                float o_ = sig2 (accA[3][r]);
                float c  = f_ * c0r[r] + i_ * g_;
                c0r[r] = c;
                float h  = o_ * tanh_u(c);
                BH[(q * 4 + r) * AS + jj] = (f16)h;
            }
            if (loader) AH[xb * AS + 128 + xf] = (f16)xpre;
            __syncthreads();
        };

        for (int s = 0; s < TT; s += 2) {
            stepL0(Phi[1], Phi[0], s);
            stepL0(Phi[0], Phi[1], s + 1);
        }
        __syncthreads();   // slot TT (layer-1 finishes h1(TT-1))
    } else {
        // ================= LAYER-1 waves =================
        f16x8 wi1[2][4];   // Wih1 (input = h0)
        f16x8 wh1[2][4];   // Whh1 (recurrent h1)
        float bu1[4];
        #pragma unroll
        for (int g = 0; g < 4; ++g) {
            const float sc = (g == 2) ? (2.0f * LOG2E) : LOG2E;
            const int n = 64 * g + jj;
            #pragma unroll
            for (int kt = 0; kt < 2; ++kt) {
                f16x8 v1, v2;
                #pragma unroll
                for (int j = 0; j < 8; ++j) {
                    const int k = kt * 32 + q * 8 + j;
                    v1[j] = (f16)(Wih1[n * H + k] * sc);
                    v2[j] = (f16)(Whh1[n * H + k] * sc);
                }
                wi1[kt][g] = v1; wh1[kt][g] = v2;
            }
            bu1[g] = (bih1[64 * g + jj] + bhh1[64 * g + jj]) * sc;
        }
        float c1r[4] = {0.f, 0.f, 0.f, 0.f};

        __syncthreads();   // slot 0 (layer-0 produces h0(0))

        // AH = plane p^1 (h0(s-1) read, h1(s-1) write); BH = plane p (h1(s-2) read)
        auto stepL1 = [&](f16* __restrict__ AH, f16* __restrict__ BH, int s) {
            f16x8 n0 = *(const f16x8*)&AH[ar + 0  + ko];
            f16x8 n1 = *(const f16x8*)&AH[ar + 32 + ko];
            f16x8 r0 = *(const f16x8*)&BH[ar + 64 + ko];
            f16x8 r1 = *(const f16x8*)&BH[ar + 96 + ko];
            f32x4 accB[4];
            #pragma unroll
            for (int g = 0; g < 4; ++g) {
                f32x4 acc = {bu1[g], bu1[g], bu1[g], bu1[g]};   // bias pre-loaded
                acc = __builtin_amdgcn_mfma_f32_16x16x32_f16(n0, wi1[0][g], acc, 0, 0, 0);
                acc = __builtin_amdgcn_mfma_f32_16x16x32_f16(n1, wi1[1][g], acc, 0, 0, 0);
                acc = __builtin_amdgcn_mfma_f32_16x16x32_f16(r0, wh1[0][g], acc, 0, 0, 0);
                acc = __builtin_amdgcn_mfma_f32_16x16x32_f16(r1, wh1[1][g], acc, 0, 0, 0);
                accB[g] = acc;
            }
            #pragma unroll
            for (int r = 0; r < 4; ++r) {
                float i_ = sig2 (accB[0][r]);
                float f_ = sig2 (accB[1][r]);
                float g_ = tanh2(accB[2][r]);
                float o_ = sig2 (accB[3][r]);
                float c  = f_ * c1r[r] + i_ * g_;
                c1r[r] = c;
                float h  = o_ * tanh_u(c);
                AH[(q * 4 + r) * AS + 64 + jj] = (f16)h;
                if (s == TT) hfin[q * 4 + r][jj] = h;
            }
            __syncthreads();
        };

        for (int s = 1; s <= TT; s += 2) {
            stepL1(Phi[0], Phi[1], s);
            stepL1(Phi[1], Phi[0], s + 1);
        }
    }

    // ---- FC epilogue ----
    if (t < NB * OUTD) {
        const int b = t / OUTD;
        const int o = t - b * OUTD;
        float a = bfc[o];
        #pragma unroll
        for (int j = 0; j < H; ++j)
            a += Wfc[o * H + j] * hfin[b][j];
        out[(size_t)(b0 + b) * OUTD + o] = a;
    }
}

extern "C" void kernel_launch(void* const* d_in, const int* in_sizes, int n_in,
                              void* d_out, int out_size, void* d_ws, size_t ws_size,
                              hipStream_t stream) {
    const float* x    = (const float*)d_in[0];
    const float* Wih0 = (const float*)d_in[1];
    const float* Whh0 = (const float*)d_in[2];
    const float* bih0 = (const float*)d_in[3];
    const float* bhh0 = (const float*)d_in[4];
    const float* Wih1 = (const float*)d_in[5];
    const float* Whh1 = (const float*)d_in[6];
    const float* bih1 = (const float*)d_in[7];
    const float* bhh1 = (const float*)d_in[8];
    const float* Wfc  = (const float*)d_in[9];
    const float* bfc  = (const float*)d_in[10];

    dim3 grid(BTOT / NB);   // 256 blocks, 1 per CU; 8 waves = 2 waves/SIMD
    dim3 block(512);
    lstm_ws<<<grid, block, 0, stream>>>(x, Wih0, Whh0, bih0, bhh0,
                                        Wih1, Whh1, bih1, bhh1,
                                        Wfc, bfc, (float*)d_out);
}

// Round 7
// 459.483 us; speedup vs baseline: 10.1612x; 1.0044x over previous
//
#include <hip/hip_runtime.h>

#define H    64
#define TT   512
#define NB   16
#define OUTD 3
#define BTOT 4096
#define INF  6

typedef _Float16 f16;
typedef _Float16 f16x8 __attribute__((ext_vector_type(8)));
typedef float    f32x4 __attribute__((ext_vector_type(4)));

// plane row stride (f16 elems): cols 0-63 h0 | 64-127 h1 | 128-135 x | pad
#define AS 168

#define LOG2E 1.44269504088896340736f
#define KSC   (2.0f * LOG2E)

// Fused LSTM cell update. Pre-activations arrive pre-scaled: ai,af,ao by
// log2e; ag by 2*log2e. C is the cell state pre-scaled by 2*log2e and is
// updated in place. Returns h. One rcp for the c-update (3 sigmo/tanh
// denominators fused) and one rcp for h = sigmoid(o)*tanh(c).
__device__ __forceinline__ float lstm_cell(float ai, float af, float ag, float ao,
                                           float& C) {
    float ei = __builtin_amdgcn_exp2f(ai);
    float ef = __builtin_amdgcn_exp2f(af);
    float eg = __builtin_amdgcn_exp2f(ag);
    float eo = __builtin_amdgcn_exp2f(ao);
    float A  = 1.0f + ei;          // sigmoid(i) = ei/A
    float F  = 1.0f + ef;          // sigmoid(f) = ef/F
    float Bp = eg + 1.0f;          // tanh(g)    = (eg-1)/Bp
    float G  = eg - 1.0f;
    float P  = A * Bp;
    float r1 = __builtin_amdgcn_rcpf(P * F);
    float n1 = ef * C * P;         // sigmoid(f)*C  * (P*F)
    float t2 = ei * G * F;         // i*g           * (P*F) / K
    C = __builtin_fmaf(KSC, t2, n1) * r1;
    // h = sigmoid(o) * tanh(c):  ec = 2^C (C already 2*log2e*c), clamped vs inf
    float ec = __builtin_amdgcn_exp2f(fminf(C, 126.0f));
    float r2 = __builtin_amdgcn_rcpf((1.0f + eo) * (ec + 1.0f));
    return eo * (ec - 1.0f) * r2;
}

// Wave-specialized layer pipeline (single-f16 state planes):
//   waves 0-3 (role 0): layer-0, compute h0(s) at slot s          (s = 0..TT-1)
//   waves 4-7 (role 1): layer-1, compute h1(s-1) at slot s        (s = 1..TT)
// One barrier per slot. h0(s) -> plane s&1 cols 0-63; h1(s-1) -> plane (s-1)&1
// cols 64-127; x(s) -> plane s&1 cols 128+. Same-slot ranges disjoint.
__launch_bounds__(512, 2)
__global__ void lstm_ws(const float* __restrict__ x,
                        const float* __restrict__ Wih0, const float* __restrict__ Whh0,
                        const float* __restrict__ bih0, const float* __restrict__ bhh0,
                        const float* __restrict__ Wih1, const float* __restrict__ Whh1,
                        const float* __restrict__ bih1, const float* __restrict__ bhh1,
                        const float* __restrict__ Wfc,  const float* __restrict__ bfc,
                        float* __restrict__ out)
{
    __shared__ __align__(16) f16 Phi[2][NB * AS];
    __shared__ float hfin[NB][H + 1];

    const int t    = threadIdx.x;
    const int u    = t & 255;
    const int role = t >> 8;
    const int wv   = u >> 6;
    const int l15  = u & 15;
    const int q    = (u >> 4) & 3;
    const int jj   = 16 * wv + l15;   // hidden column this thread owns (all 4 gates)
    const int b0   = blockIdx.x * NB;
    const int ar   = l15 * AS;
    const int ko   = q * 8;

    // ---- zero both planes ----
    {
        f16* ph = &Phi[0][0];
        for (int idx = t; idx < 2 * NB * AS; idx += 512) ph[idx] = (f16)0.0f;
    }
    __syncthreads();   // zeroing complete before x(0) store

    const bool loader = (role == 0) && (u < NB * INF);
    const int  xb = u / INF;
    const int  xf = u - xb * INF;
    if (loader)
        Phi[0][xb * AS + 128 + xf] = (f16)x[((size_t)(b0 + xb) * TT) * INF + xf];
    __syncthreads();

    if (role == 0) {
        // ================= LAYER-0 waves =================
        f16x8 wh0[2][4];   // Whh0 fragments, pre-scaled
        f16x8 wx0[4];      // Wih0 x-tile (k<6 valid on q==0)
        float bu0[4];
        #pragma unroll
        for (int g = 0; g < 4; ++g) {
            const float sc = (g == 2) ? (2.0f * LOG2E) : LOG2E;
            const int n = 64 * g + jj;
            #pragma unroll
            for (int kt = 0; kt < 2; ++kt) {
                f16x8 v;
                #pragma unroll
                for (int j = 0; j < 8; ++j)
                    v[j] = (f16)(Whh0[n * H + kt * 32 + q * 8 + j] * sc);
                wh0[kt][g] = v;
            }
            f16x8 vx;
            #pragma unroll
            for (int j = 0; j < 8; ++j)
                vx[j] = (q == 0 && j < INF) ? (f16)(Wih0[n * INF + j] * sc) : (f16)0.0f;
            wx0[g] = vx;
            bu0[g] = (bih0[64 * g + jj] + bhh0[64 * g + jj]) * sc;
        }
        float c0r[4] = {0.f, 0.f, 0.f, 0.f};   // pre-scaled by 2*log2e
        float xpre = 0.0f;

        // AH = plane p^1 (h0(s-1) read, x(s+1) write); BH = plane p (x(s) read, h0(s) write)
        auto stepL0 = [&](f16* __restrict__ AH, f16* __restrict__ BH, int s) {
            if (loader) {
                const int tn = (s + 1 < TT) ? (s + 1) : (TT - 1);
                xpre = x[((size_t)(b0 + xb) * TT + tn) * INF + xf];
            }
            f16x8 a0 = *(const f16x8*)&AH[ar + 0   + ko];
            f16x8 a1 = *(const f16x8*)&AH[ar + 32  + ko];
            f16x8 ax = *(const f16x8*)&BH[ar + 128 + ko];
            f32x4 accA[4];
            #pragma unroll
            for (int g = 0; g < 4; ++g) {
                f32x4 acc = {bu0[g], bu0[g], bu0[g], bu0[g]};   // bias pre-loaded
                acc = __builtin_amdgcn_mfma_f32_16x16x32_f16(a0, wh0[0][g], acc, 0, 0, 0);
                acc = __builtin_amdgcn_mfma_f32_16x16x32_f16(a1, wh0[1][g], acc, 0, 0, 0);
                acc = __builtin_amdgcn_mfma_f32_16x16x32_f16(ax, wx0[g],    acc, 0, 0, 0);
                accA[g] = acc;
            }
            #pragma unroll
            for (int r = 0; r < 4; ++r) {
                float h = lstm_cell(accA[0][r], accA[1][r], accA[2][r], accA[3][r], c0r[r]);
                BH[(q * 4 + r) * AS + jj] = (f16)h;
            }
            if (loader) AH[xb * AS + 128 + xf] = (f16)xpre;
            __syncthreads();
        };

        for (int s = 0; s < TT; s += 2) {
            stepL0(Phi[1], Phi[0], s);
            stepL0(Phi[0], Phi[1], s + 1);
        }
        __syncthreads();   // slot TT (layer-1 finishes h1(TT-1))
    } else {
        // ================= LAYER-1 waves =================
        f16x8 wi1[2][4];   // Wih1 (input = h0)
        f16x8 wh1[2][4];   // Whh1 (recurrent h1)
        float bu1[4];
        #pragma unroll
        for (int g = 0; g < 4; ++g) {
            const float sc = (g == 2) ? (2.0f * LOG2E) : LOG2E;
            const int n = 64 * g + jj;
            #pragma unroll
            for (int kt = 0; kt < 2; ++kt) {
                f16x8 v1, v2;
                #pragma unroll
                for (int j = 0; j < 8; ++j) {
                    const int k = kt * 32 + q * 8 + j;
                    v1[j] = (f16)(Wih1[n * H + k] * sc);
                    v2[j] = (f16)(Whh1[n * H + k] * sc);
                }
                wi1[kt][g] = v1; wh1[kt][g] = v2;
            }
            bu1[g] = (bih1[64 * g + jj] + bhh1[64 * g + jj]) * sc;
        }
        float c1r[4] = {0.f, 0.f, 0.f, 0.f};   // pre-scaled by 2*log2e

        __syncthreads();   // slot 0 (layer-0 produces h0(0))

        // AH = plane p^1 (h0(s-1) read, h1(s-1) write); BH = plane p (h1(s-2) read)
        auto stepL1 = [&](f16* __restrict__ AH, f16* __restrict__ BH, int s) {
            f16x8 n0 = *(const f16x8*)&AH[ar + 0  + ko];
            f16x8 n1 = *(const f16x8*)&AH[ar + 32 + ko];
            f16x8 r0 = *(const f16x8*)&BH[ar + 64 + ko];
            f16x8 r1 = *(const f16x8*)&BH[ar + 96 + ko];
            f32x4 accB[4];
            #pragma unroll
            for (int g = 0; g < 4; ++g) {
                f32x4 acc = {bu1[g], bu1[g], bu1[g], bu1[g]};   // bias pre-loaded
                acc = __builtin_amdgcn_mfma_f32_16x16x32_f16(n0, wi1[0][g], acc, 0, 0, 0);
                acc = __builtin_amdgcn_mfma_f32_16x16x32_f16(n1, wi1[1][g], acc, 0, 0, 0);
                acc = __builtin_amdgcn_mfma_f32_16x16x32_f16(r0, wh1[0][g], acc, 0, 0, 0);
                acc = __builtin_amdgcn_mfma_f32_16x16x32_f16(r1, wh1[1][g], acc, 0, 0, 0);
                accB[g] = acc;
            }
            #pragma unroll
            for (int r = 0; r < 4; ++r) {
                float h = lstm_cell(accB[0][r], accB[1][r], accB[2][r], accB[3][r], c1r[r]);
                AH[(q * 4 + r) * AS + 64 + jj] = (f16)h;
                if (s == TT) hfin[q * 4 + r][jj] = h;
            }
            __syncthreads();
        };

        for (int s = 1; s <= TT; s += 2) {
            stepL1(Phi[0], Phi[1], s);
            stepL1(Phi[1], Phi[0], s + 1);
        }
    }

    // ---- FC epilogue ----
    if (t < NB * OUTD) {
        const int b = t / OUTD;
        const int o = t - b * OUTD;
        float a = bfc[o];
        #pragma unroll
        for (int j = 0; j < H; ++j)
            a += Wfc[o * H + j] * hfin[b][j];
        out[(size_t)(b0 + b) * OUTD + o] = a;
    }
}

extern "C" void kernel_launch(void* const* d_in, const int* in_sizes, int n_in,
                              void* d_out, int out_size, void* d_ws, size_t ws_size,
                              hipStream_t stream) {
    const float* x    = (const float*)d_in[0];
    const float* Wih0 = (const float*)d_in[1];
    const float* Whh0 = (const float*)d_in[2];
    const float* bih0 = (const float*)d_in[3];
    const float* bhh0 = (const float*)d_in[4];
    const float* Wih1 = (const float*)d_in[5];
    const float* Whh1 = (const float*)d_in[6];
    const float* bih1 = (const float*)d_in[7];
    const float* bhh1 = (const float*)d_in[8];
    const float* Wfc  = (const float*)d_in[9];
    const float* bfc  = (const float*)d_in[10];

    dim3 grid(BTOT / NB);   // 256 blocks, 1 per CU; 8 waves = 2 waves/SIMD
    dim3 block(512);
    lstm_ws<<<grid, block, 0, stream>>>(x, Wih0, Whh0, bih0, bhh0,
                                        Wih1, Whh1, bih1, bhh1,
                                        Wfc, bfc, (float*)d_out);
}